// Round 4
// baseline (1945.086 us; speedup 1.0000x reference)
//
#include <hip/hip_runtime.h>
#include <math.h>

// Sinkhorn via potentials: log_pi after iter i = A - u_i - v_i,
//   v_i[g,e] = LSE_n(A - u_{i-1}),  u_i[n,g] = LSE_e(A - v_i),  u_0 = 0.
// Base-2 throughout (v_exp_f32 is native 2^x).
// ws layout (floats): [0:1024] v ; [1024 + r*1024 ...] col-sum replicas r=0..7.

#define NTOK 131072
#define NCOL 1024
#define NBLK 1024
#define RPW  32           // NTOK / (NBLK * 4 waves)
#define NREP 8

constexpr float KLOG = 28.85390081777927f;  // log2(e) / 0.05
constexpr float SMAX = 8.0f;                // safe bound on max |normal sample|

__global__ __launch_bounds__(256) void sk_init(const float* __restrict__ sc,
                                               const float* __restrict__ bs,
                                               float* __restrict__ ws) {
    int c = blockIdx.x * 256 + threadIdx.x;   // grid 4x256 -> 1024
    int g = c >> 7;
    // v0 = analytic upper bound on column max of A2
    ws[c] = fmaf(SMAX, sc[g] * KLOG, bs[g] * KLOG);
#pragma unroll
    for (int r = 0; r < NREP; ++r) ws[NCOL + r * NCOL + c] = 0.0f;
}

__global__ __launch_bounds__(256) void sk_fin(float* __restrict__ ws) {
    int c = blockIdx.x * 256 + threadIdx.x;
    float s = 0.0f;
#pragma unroll
    for (int r = 0; r < NREP; ++r) {
        s += ws[NCOL + r * NCOL + c];
        ws[NCOL + r * NCOL + c] = 0.0f;     // re-zero for next accumulation
    }
    ws[c] += log2f(s);                      // v += log2(col sum)
}

template <bool ROWRED, bool WRITEOUT>
__global__ __launch_bounds__(256, 4) void sk_pass(const float* __restrict__ mixes,
                                                  const float* __restrict__ sc,
                                                  const float* __restrict__ bs,
                                                  float* __restrict__ ws,
                                                  float* __restrict__ out) {
    const int tid  = threadIdx.x;
    const int lane = tid & 63;
    const int wv   = tid >> 6;      // wave in block, 0..3
    const int hi   = lane >> 5;     // half-wave -> which group of the pair

    // lane's columns: c(k,j) = 256*k + 4*lane + j, k=0..3, j=0..3; group g = 2k+hi
    float sc2[4], bv[4][4];
#pragma unroll
    for (int k = 0; k < 4; ++k) {
        const int g = 2 * k + hi;
        sc2[k] = sc[g] * KLOG;
        const float b2 = bs[g] * KLOG;
        const float4 vv = reinterpret_cast<const float4*>(ws)[64 * k + lane];
        bv[k][0] = b2 - vv.x; bv[k][1] = b2 - vv.y;
        bv[k][2] = b2 - vv.z; bv[k][3] = b2 - vv.w;
    }

    const int gw = blockIdx.x * 4 + wv;           // global wave id 0..4095
    const size_t row0 = (size_t)gw * RPW;

    float acc[4][4];
#pragma unroll
    for (int k = 0; k < 4; ++k)
#pragma unroll
        for (int j = 0; j < 4; ++j) acc[k][j] = 0.0f;

    for (int r = 0; r < RPW; ++r) {
        const float4* rp = reinterpret_cast<const float4*>(mixes + (row0 + r) * NCOL);
        float4 d[4];
#pragma unroll
        for (int k = 0; k < 4; ++k) d[k] = rp[64 * k + lane];

#pragma unroll
        for (int k = 0; k < 4; ++k) {
            float x0 = fmaf(d[k].x, sc2[k], bv[k][0]);
            float x1 = fmaf(d[k].y, sc2[k], bv[k][1]);
            float x2 = fmaf(d[k].z, sc2[k], bv[k][2]);
            float x3 = fmaf(d[k].w, sc2[k], bv[k][3]);
            if constexpr (!ROWRED) {
                // first pass: u_0 = 0; terms 2^(A2 - v0) <= 1 by analytic bound
                acc[k][0] += __builtin_exp2f(x0);
                acc[k][1] += __builtin_exp2f(x1);
                acc[k][2] += __builtin_exp2f(x2);
                acc[k][3] += __builtin_exp2f(x3);
            } else {
                // row LSE over this group's 128 cols (32 lanes x 4 vals)
                float m = fmaxf(fmaxf(x0, x1), fmaxf(x2, x3));
#pragma unroll
                for (int s = 16; s >= 1; s >>= 1)
                    m = fmaxf(m, __shfl_xor(m, s, 64));
                float t0 = __builtin_exp2f(x0 - m);
                float t1 = __builtin_exp2f(x1 - m);
                float t2 = __builtin_exp2f(x2 - m);
                float t3 = __builtin_exp2f(x3 - m);
                float S = (t0 + t1) + (t2 + t3);
#pragma unroll
                for (int s = 16; s >= 1; s >>= 1)
                    S += __shfl_xor(S, s, 64);
                const float rS = 1.0f / S;   // 2^(x-u) = 2^(x-m)/S
                if constexpr (WRITEOUT) {
                    float4* op = reinterpret_cast<float4*>(out + (row0 + r) * NCOL);
                    op[64 * k + lane] = make_float4(t0 * rS, t1 * rS, t2 * rS, t3 * rS);
                } else {
                    acc[k][0] += t0 * rS; acc[k][1] += t1 * rS;
                    acc[k][2] += t2 * rS; acc[k][3] += t3 * rS;
                }
            }
        }
    }

    if constexpr (!WRITEOUT) {
        __shared__ float sacc[4][NCOL];
#pragma unroll
        for (int k = 0; k < 4; ++k)
            reinterpret_cast<float4*>(&sacc[wv][256 * k])[lane] =
                make_float4(acc[k][0], acc[k][1], acc[k][2], acc[k][3]);
        __syncthreads();
        float* rep = ws + NCOL + (size_t)(blockIdx.x & (NREP - 1)) * NCOL;
#pragma unroll
        for (int i = 0; i < 4; ++i) {
            const int c = tid + 256 * i;
            const float s = (sacc[0][c] + sacc[1][c]) + (sacc[2][c] + sacc[3][c]);
            atomicAdd(&rep[c], s);
        }
    }
}

extern "C" void kernel_launch(void* const* d_in, const int* in_sizes, int n_in,
                              void* d_out, int out_size, void* d_ws, size_t ws_size,
                              hipStream_t stream) {
    const float* mixes = (const float*)d_in[0];
    const float* sc    = (const float*)d_in[1];
    const float* bs    = (const float*)d_in[2];
    float* out = (float*)d_out;
    float* ws  = (float*)d_ws;

    sk_init<<<4, 256, 0, stream>>>(sc, bs, ws);

    // pass 1: col sums with u_0 = 0 (no row reduce)
    sk_pass<false, false><<<NBLK, 256, 0, stream>>>(mixes, sc, bs, ws, out);
    sk_fin<<<4, 256, 0, stream>>>(ws);

    // passes 2..8: fused row-LSE (u_{t-1}) + col sums (v_t)
    for (int t = 0; t < 7; ++t) {
        sk_pass<true, false><<<NBLK, 256, 0, stream>>>(mixes, sc, bs, ws, out);
        sk_fin<<<4, 256, 0, stream>>>(ws);
    }

    // output pass: u_8 row-LSE vs v_8, write exp(A - u - v)
    sk_pass<true, true><<<NBLK, 256, 0, stream>>>(mixes, sc, bs, ws, out);
}

// Round 10
// 1754.975 us; speedup vs baseline: 1.1083x; 1.1083x over previous
//
#include <hip/hip_runtime.h>
#include <math.h>

// Sinkhorn via potentials: log_pi after iter i = A - u_i - v_i,
//   v_i[g,e] = LSE_n(A - u_{i-1}),  u_i[n,g] = LSE_e(A - v_i),  u_0 = 0.
// Base-2 throughout (v_exp_f32 is native 2^x).
// ws layout (floats): [0:1024] v ; [1024 + r*1024 ...] col-sum replicas r=0..7.

#define NTOK 131072
#define NCOL 1024
#define NBLK 2048
#define RPW  16           // NTOK / (NBLK * 4 waves)
#define NREP 8

constexpr float KLOG = 28.85390081777927f;  // log2(e) / 0.05
constexpr float SMAX = 8.0f;                // safe bound on max |normal sample|

__global__ __launch_bounds__(256) void sk_init(const float* __restrict__ sc,
                                               const float* __restrict__ bs,
                                               float* __restrict__ ws) {
    int c = blockIdx.x * 256 + threadIdx.x;   // grid 4x256 -> 1024
    int g = c >> 7;
    // v0 = analytic upper bound on column max of A2
    ws[c] = fmaf(SMAX, sc[g] * KLOG, bs[g] * KLOG);
#pragma unroll
    for (int r = 0; r < NREP; ++r) ws[NCOL + r * NCOL + c] = 0.0f;
}

__global__ __launch_bounds__(256) void sk_fin(float* __restrict__ ws) {
    int c = blockIdx.x * 256 + threadIdx.x;
    float s = 0.0f;
#pragma unroll
    for (int r = 0; r < NREP; ++r) {
        s += ws[NCOL + r * NCOL + c];
        ws[NCOL + r * NCOL + c] = 0.0f;     // re-zero for next accumulation
    }
    ws[c] += log2f(s);                      // v += log2(col sum)
}

template <bool ROWRED, bool WRITEOUT>
__global__ __launch_bounds__(256) void sk_pass(const float* __restrict__ mixes,
                                               const float* __restrict__ sc,
                                               const float* __restrict__ bs,
                                               float* __restrict__ ws,
                                               float* __restrict__ out) {
    const int tid  = threadIdx.x;
    const int lane = tid & 63;
    const int wv   = tid >> 6;      // wave in block, 0..3
    const int hi   = lane >> 5;     // half-wave -> which group of the pair

    // lane's columns: c(k,j) = 256*k + 4*lane + j, k=0..3, j=0..3; group g = 2k+hi
    float sc2[4], bv[4][4];
#pragma unroll
    for (int k = 0; k < 4; ++k) {
        const int g = 2 * k + hi;
        sc2[k] = sc[g] * KLOG;
        const float b2 = bs[g] * KLOG;
        const float4 vv = reinterpret_cast<const float4*>(ws)[64 * k + lane];
        bv[k][0] = b2 - vv.x; bv[k][1] = b2 - vv.y;
        bv[k][2] = b2 - vv.z; bv[k][3] = b2 - vv.w;
    }

    const int gw = blockIdx.x * 4 + wv;           // global wave id 0..8191
    const size_t row0 = (size_t)gw * RPW;

    float acc[4][4];
#pragma unroll
    for (int k = 0; k < 4; ++k)
#pragma unroll
        for (int j = 0; j < 4; ++j) acc[k][j] = 0.0f;

    // prime the software pipeline: row 0 in flight
    float4 d[4];
    {
        const float4* rp = reinterpret_cast<const float4*>(mixes + row0 * NCOL);
#pragma unroll
        for (int k = 0; k < 4; ++k) d[k] = rp[64 * k + lane];
    }

    for (int r = 0; r < RPW; ++r) {
        // issue next row's loads BEFORE this row's compute (1-row lookahead)
        const int rn = (r + 1 < RPW) ? (r + 1) : r;   // last iter: re-load (L1-hot, unused path kept simple)
        const float4* rq = reinterpret_cast<const float4*>(mixes + (row0 + rn) * NCOL);
        float4 dn[4];
#pragma unroll
        for (int k = 0; k < 4; ++k) dn[k] = rq[64 * k + lane];

#pragma unroll
        for (int k = 0; k < 4; ++k) {
            float x0 = fmaf(d[k].x, sc2[k], bv[k][0]);
            float x1 = fmaf(d[k].y, sc2[k], bv[k][1]);
            float x2 = fmaf(d[k].z, sc2[k], bv[k][2]);
            float x3 = fmaf(d[k].w, sc2[k], bv[k][3]);
            if constexpr (!ROWRED) {
                // first pass: u_0 = 0; terms 2^(A2 - v0) <= 1 by analytic bound
                acc[k][0] += __builtin_exp2f(x0);
                acc[k][1] += __builtin_exp2f(x1);
                acc[k][2] += __builtin_exp2f(x2);
                acc[k][3] += __builtin_exp2f(x3);
            } else {
                // row LSE over this group's 128 cols (32 lanes x 4 vals)
                float m = fmaxf(fmaxf(x0, x1), fmaxf(x2, x3));
#pragma unroll
                for (int s = 16; s >= 1; s >>= 1)
                    m = fmaxf(m, __shfl_xor(m, s, 64));
                float t0 = __builtin_exp2f(x0 - m);
                float t1 = __builtin_exp2f(x1 - m);
                float t2 = __builtin_exp2f(x2 - m);
                float t3 = __builtin_exp2f(x3 - m);
                float S = (t0 + t1) + (t2 + t3);
#pragma unroll
                for (int s = 16; s >= 1; s >>= 1)
                    S += __shfl_xor(S, s, 64);
                const float rS = 1.0f / S;   // 2^(x-u) = 2^(x-m)/S
                if constexpr (WRITEOUT) {
                    float4* op = reinterpret_cast<float4*>(out + (row0 + r) * NCOL);
                    op[64 * k + lane] = make_float4(t0 * rS, t1 * rS, t2 * rS, t3 * rS);
                } else {
                    acc[k][0] += t0 * rS; acc[k][1] += t1 * rS;
                    acc[k][2] += t2 * rS; acc[k][3] += t3 * rS;
                }
            }
        }

#pragma unroll
        for (int k = 0; k < 4; ++k) d[k] = dn[k];
    }

    if constexpr (!WRITEOUT) {
        __shared__ float sacc[4][NCOL];
#pragma unroll
        for (int k = 0; k < 4; ++k)
            reinterpret_cast<float4*>(&sacc[wv][256 * k])[lane] =
                make_float4(acc[k][0], acc[k][1], acc[k][2], acc[k][3]);
        __syncthreads();
        float* rep = ws + NCOL + (size_t)(blockIdx.x & (NREP - 1)) * NCOL;
#pragma unroll
        for (int i = 0; i < 4; ++i) {
            const int c = tid + 256 * i;
            const float s = (sacc[0][c] + sacc[1][c]) + (sacc[2][c] + sacc[3][c]);
            atomicAdd(&rep[c], s);
        }
    }
}

extern "C" void kernel_launch(void* const* d_in, const int* in_sizes, int n_in,
                              void* d_out, int out_size, void* d_ws, size_t ws_size,
                              hipStream_t stream) {
    const float* mixes = (const float*)d_in[0];
    const float* sc    = (const float*)d_in[1];
    const float* bs    = (const float*)d_in[2];
    float* out = (float*)d_out;
    float* ws  = (float*)d_ws;

    sk_init<<<4, 256, 0, stream>>>(sc, bs, ws);

    // pass 1: col sums with u_0 = 0 (no row reduce)
    sk_pass<false, false><<<NBLK, 256, 0, stream>>>(mixes, sc, bs, ws, out);
    sk_fin<<<4, 256, 0, stream>>>(ws);

    // passes 2..8: fused row-LSE (u_{t-1}) + col sums (v_t)
    for (int t = 0; t < 7; ++t) {
        sk_pass<true, false><<<NBLK, 256, 0, stream>>>(mixes, sc, bs, ws, out);
        sk_fin<<<4, 256, 0, stream>>>(ws);
    }

    // output pass: u_8 row-LSE vs v_8, write exp(A - u - v)
    sk_pass<true, true><<<NBLK, 256, 0, stream>>>(mixes, sc, bs, ws, out);
}